// Round 3
// baseline (95.725 us; speedup 1.0000x reference)
//
#include <hip/hip_runtime.h>
#include <math.h>

// out = |<0| U(f2)^dag U(f1) |0>|^2 for the 4-qubit embedding circuit.
// Each layer = (diagonal phase P) * (H^x4) = diag(P) * WHT16 / 4, where P folds
// all RZ + ZZ phases (they commute past H's on other wires).
// Fused form (all 1/4 factors folded into one final 1/4096 constant):
//   t = P1                                  (layer 1 on |0>: W|0> = ones)
//   t = P1 o (W t) ; t = P1 o (W t)         (forward layers 2,3)
//   t = conj(P2) o t
//   t = conj(P2) o (W t) ; t = conj(P2) o (W t)
//   amp0 = sum(t) / 4096
// One thread per sample; state (16 complex) + one phase table live in VGPRs.

#define PI_F 3.14159265358979323846f

__device__ __forceinline__ void fast_sincos(float x, float& s, float& c) {
    const float INV2PI = 0.15915494309189535f;
    const float TWOPI  = 6.283185307179586f;
    float k = rintf(x * INV2PI);
    float r = fmaf(-k, TWOPI, x);   // r in ~[-pi, pi]
    s = __sinf(r);
    c = __cosf(r);
}

// Unscaled phase table. Wire w maps to bit (3-w): wire0->mask8 ... wire3->mask1.
// phi(s) = -sum_j f_j*sigma_j + sum_{(a,b) in ring} (pi-f_a)(pi-f_b)*sigma_a*sigma_b
__device__ __forceinline__ void phase_table(const float f[4], float cs[16], float sn[16]) {
    float g0 = PI_F - f[0], g1 = PI_F - f[1], g2 = PI_F - f[2], g3 = PI_F - f[3];
    float p01 = g0 * g1, p12 = g1 * g2, p23 = g2 * g3, p30 = g3 * g0;
    // linear-part butterfly: L(s) = lin01[(s>>2)&3] + lin23[s&3]
    float u = f[0] + f[1], v = f[0] - f[1];
    float lin01[4] = {u, v, -v, -u};        // (sig0,sig1) = (-,-),(-,+),(+,-),(+,+)
    float w = f[2] + f[3], z = f[2] - f[3];
    float lin23[4] = {w, z, -z, -w};
#pragma unroll
    for (int s = 0; s < 16; ++s) {
        const float s0 = (s & 8) ? 1.f : -1.f;
        const float s1 = (s & 4) ? 1.f : -1.f;
        const float s2 = (s & 2) ? 1.f : -1.f;
        const float s3 = (s & 1) ? 1.f : -1.f;
        float phi = lin01[(s >> 2) & 3] + lin23[s & 3]
                  + p01 * (s0 * s1) + p12 * (s1 * s2)
                  + p23 * (s2 * s3) + p30 * (s3 * s0);
        fast_sincos(phi, sn[s], cs[s]);
    }
}

// unscaled 16-pt Walsh-Hadamard on one real array
__device__ __forceinline__ void wht16(float a[16]) {
#pragma unroll
    for (int m = 1; m < 16; m <<= 1) {
#pragma unroll
        for (int s = 0; s < 16; ++s) {
            if (!(s & m)) {
                float x = a[s], y = a[s | m];
                a[s] = x + y; a[s | m] = x - y;
            }
        }
    }
}

// t = P o t  (forward) or t = conj(P) o t (CONJ=true)
template <bool CONJ>
__device__ __forceinline__ void diag_mul(float re[16], float im[16],
                                         const float cs[16], const float sn[16]) {
#pragma unroll
    for (int s = 0; s < 16; ++s) {
        float r, i;
        if (CONJ) {
            r = fmaf(re[s], cs[s],  im[s] * sn[s]);
            i = fmaf(im[s], cs[s], -re[s] * sn[s]);
        } else {
            r = fmaf(re[s], cs[s], -im[s] * sn[s]);
            i = fmaf(im[s], cs[s],  re[s] * sn[s]);
        }
        re[s] = r; im[s] = i;
    }
}

// MLP 4->8->8->4 on two inputs simultaneously (weight loads shared/scalar).
__device__ __forceinline__ void mlp_dual(
    const float xa[4], const float xb[4],
    const float* __restrict__ W1, const float* __restrict__ b1,
    const float* __restrict__ W2, const float* __restrict__ b2,
    const float* __restrict__ W3, const float* __restrict__ b3,
    float fa[4], float fb[4]) {
    float h1a[8], h1b[8];
#pragma unroll
    for (int k = 0; k < 8; ++k) {
        float aa = b1[k], ab = aa;
#pragma unroll
        for (int j = 0; j < 4; ++j) {
            float wv = W1[j * 8 + k];
            aa = fmaf(xa[j], wv, aa);
            ab = fmaf(xb[j], wv, ab);
        }
        h1a[k] = fmaxf(aa, 0.f);
        h1b[k] = fmaxf(ab, 0.f);
    }
    float h2a[8], h2b[8];
#pragma unroll
    for (int k = 0; k < 8; ++k) {
        float aa = b2[k], ab = aa;
#pragma unroll
        for (int j = 0; j < 8; ++j) {
            float wv = W2[j * 8 + k];
            aa = fmaf(h1a[j], wv, aa);
            ab = fmaf(h1b[j], wv, ab);
        }
        h2a[k] = fmaxf(aa, 0.f);
        h2b[k] = fmaxf(ab, 0.f);
    }
#pragma unroll
    for (int k = 0; k < 4; ++k) {
        float aa = b3[k], ab = aa;
#pragma unroll
        for (int j = 0; j < 8; ++j) {
            float wv = W3[j * 4 + k];
            aa = fmaf(h2a[j], wv, aa);
            ab = fmaf(h2b[j], wv, ab);
        }
        fa[k] = aa;
        fb[k] = ab;
    }
}

__global__ __launch_bounds__(256) void fidelity_kernel(
    const float* __restrict__ x1, const float* __restrict__ x2,
    const float* __restrict__ W1, const float* __restrict__ b1,
    const float* __restrict__ W2, const float* __restrict__ b2,
    const float* __restrict__ W3, const float* __restrict__ b3,
    float* __restrict__ out, int n) {
    int tid = blockIdx.x * 256 + threadIdx.x;
    if (tid >= n) return;

    float4 a4 = ((const float4*)x1)[tid];
    float4 b4 = ((const float4*)x2)[tid];
    float xa[4] = {a4.x, a4.y, a4.z, a4.w};
    float xb[4] = {b4.x, b4.y, b4.z, b4.w};

    float fa[4], fb[4];
    mlp_dual(xa, xb, W1, b1, W2, b2, W3, b3, fa, fb);

    float cs[16], sn[16];
    float re[16], im[16];

    // forward: t = P1; two layers of (WHT, oP1)
    phase_table(fa, cs, sn);
#pragma unroll
    for (int s = 0; s < 16; ++s) { re[s] = cs[s]; im[s] = sn[s]; }
#pragma unroll
    for (int l = 0; l < 2; ++l) {
        wht16(re); wht16(im);
        diag_mul<false>(re, im, cs, sn);
    }

    // adjoint: oconj(P2); two layers of (WHT, oconj(P2)); final WHT row 0 = sum
    phase_table(fb, cs, sn);
    diag_mul<true>(re, im, cs, sn);
#pragma unroll
    for (int l = 0; l < 2; ++l) {
        wht16(re); wht16(im);
        diag_mul<true>(re, im, cs, sn);
    }

    float dr = 0.f, di = 0.f;
#pragma unroll
    for (int s = 0; s < 16; ++s) { dr += re[s]; di += im[s]; }
    const float SC = 1.0f / 4096.0f;   // six layers x (1/4) from H^x4
    dr *= SC; di *= SC;
    out[tid] = fmaf(dr, dr, di * di);
}

extern "C" void kernel_launch(void* const* d_in, const int* in_sizes, int n_in,
                              void* d_out, int out_size, void* d_ws, size_t ws_size,
                              hipStream_t stream) {
    const float* x1 = (const float*)d_in[0];
    const float* x2 = (const float*)d_in[1];
    const float* W1 = (const float*)d_in[2];
    const float* b1 = (const float*)d_in[3];
    const float* W2 = (const float*)d_in[4];
    const float* b2 = (const float*)d_in[5];
    const float* W3 = (const float*)d_in[6];
    const float* b3 = (const float*)d_in[7];
    float* out = (float*)d_out;

    int n = out_size;  // B samples
    int block = 256;
    int grid = (n + block - 1) / block;
    fidelity_kernel<<<grid, block, 0, stream>>>(x1, x2, W1, b1, W2, b2, W3, b3, out, n);
}